// Round 2
// baseline (207.172 us; speedup 1.0000x reference)
//
#include <hip/hip_runtime.h>
#include <stdint.h>

typedef __attribute__((ext_vector_type(8))) short short8;   // 8 bf16 (4 VGPRs) MFMA operand
typedef __attribute__((ext_vector_type(4))) float floatx4;  // MFMA accumulator

#define NPTS 256   // points per group
#define DIM  256   // feature dim
#define TILE 128   // output tile per block
#define BK   128   // K-step (2 iterations over DIM=256)
#define LDSS 136   // LDS row stride in bf16 elems (128 + 8 pad; 272 B rows, 16B-aligned)

// round-to-nearest-even fp32 -> bf16, returning the rounded fp32 value and bits<<16
static __device__ __forceinline__ uint32_t rne_hi(float f) {
    uint32_t u = __builtin_bit_cast(uint32_t, f);
    u += 0x7FFFu + ((u >> 16) & 1u);
    return u & 0xFFFF0000u;            // bf16 value in high 16 bits
}
static __device__ __forceinline__ float hi_val(uint32_t hi) {
    return __builtin_bit_cast(float, hi);
}

// ---------------------------------------------------------------------------
// One kernel does everything: per (group, tile) it stages fp32 -> bf16 into
// LDS, computes the 128 row / 128 col squared norms of the *rounded* values
// on the fly (width-32 shuffle reduce: each half-wave stages one row-slice),
// runs the 128x128x256 bf16 MFMA Gram tile, then a fused distance epilogue
// (sqrt(max(x2+y2-2S,0)), diagonal zeroed for XX/YY) -> block reduce -> one
// atomicAdd. grid = (10, G): t 0..3 = XY (w=+1), 4..6 = XX upper-tri
// (w=-0.5/-1/-0.5, off-diag tile double-counted via w), 7..9 = YY upper-tri.
// LDS ~69.6 KB -> 2 blocks/CU so stage-VALU overlaps the other block's MFMA.
// ---------------------------------------------------------------------------
__global__ __launch_bounds__(256)
void mmd_fused(const float* __restrict__ X, const float* __restrict__ Y,
               float* __restrict__ out, float scale) {
    const int g = blockIdx.y;
    const int t = blockIdx.x;

    int ptype, ti, tj; float w;
    if (t < 4)      { ptype = 0; ti = t >> 1; tj = t & 1; w = 1.0f; }
    else if (t < 7) { int u = t - 4; ptype = 1; ti = (u == 2); tj = (u >= 1); w = (u == 1) ? -1.0f : -0.5f; }
    else            { int u = t - 7; ptype = 2; ti = (u == 2); tj = (u >= 1); w = (u == 1) ? -1.0f : -0.5f; }

    const float *Pf, *Qf;
    if (ptype == 0)      { Pf = X; Qf = Y; }
    else if (ptype == 1) { Pf = X; Qf = X; }
    else                 { Pf = Y; Qf = Y; }
    const bool symdiag = (ptype != 0) && (ti == tj);

    const size_t prow0 = (size_t)g * NPTS + (size_t)ti * TILE;
    const size_t qrow0 = (size_t)g * NPTS + (size_t)tj * TILE;

    __shared__ uint16_t As[TILE * LDSS];   // 34816 B
    __shared__ uint16_t Bs[TILE * LDSS];   // 34816 B
    __shared__ float rnorm[TILE];
    __shared__ float cnorm[TILE];
    __shared__ float wpart[4];

    const int tid  = threadIdx.x;
    const int lane = tid & 63;
    const int wv   = tid >> 6;
    const int wrow = (wv >> 1) * 64;
    const int wcol = (wv & 1) * 64;
    const int quad = lane >> 4;
    const int l15  = lane & 15;

    floatx4 acc[4][4];
    #pragma unroll
    for (int i = 0; i < 4; ++i)
        #pragma unroll
        for (int j = 0; j < 4; ++j) acc[i][j] = (floatx4)0.0f;

    #pragma unroll
    for (int iter = 0; iter < 2; ++iter) {
        const int kk = iter * BK;
        if (iter) __syncthreads();          // previous MFMA phase done reading LDS

        // ---- stage 128x128 fp32 of P and Q -> bf16 LDS, norms on the fly ----
        // f = tid + i*256: row = f>>5 (0..127), col4 = (f&31)*4.
        // Lanes 0..31 of a wave share one row; lanes 32..63 the next row.
        #pragma unroll
        for (int i = 0; i < 16; ++i) {
            const int f   = tid + i * 256;
            const int row = f >> 5;
            const int c4  = (f & 31) << 2;          // float offset within BK slice

            const float4 vp = *(const float4*)(Pf + (prow0 + row) * DIM + kk + c4);
            const float4 vq = *(const float4*)(Qf + (qrow0 + row) * DIM + kk + c4);

            uint32_t p0 = rne_hi(vp.x), p1 = rne_hi(vp.y), p2 = rne_hi(vp.z), p3 = rne_hi(vp.w);
            uint32_t q0 = rne_hi(vq.x), q1 = rne_hi(vq.y), q2 = rne_hi(vq.z), q3 = rne_hi(vq.w);

            uint2 pp = { (p0 >> 16) | p1, (p2 >> 16) | p3 };
            uint2 qq = { (q0 >> 16) | q1, (q2 >> 16) | q3 };
            *(uint2*)&As[row * LDSS + c4] = pp;
            *(uint2*)&Bs[row * LDSS + c4] = qq;

            float a0 = hi_val(p0), a1 = hi_val(p1), a2 = hi_val(p2), a3 = hi_val(p3);
            float b0 = hi_val(q0), b1 = hi_val(q1), b2 = hi_val(q2), b3 = hi_val(q3);
            float sp = a0 * a0 + a1 * a1 + a2 * a2 + a3 * a3;
            float sq = b0 * b0 + b1 * b1 + b2 * b2 + b3 * b3;

            #pragma unroll
            for (int off = 16; off; off >>= 1) {    // width-32 reduce; lanes 0 & 32 clean
                sp += __shfl_down(sp, off);
                sq += __shfl_down(sq, off);
            }
            if ((lane & 31) == 0) {
                if (iter == 0) { rnorm[row] = sp;  cnorm[row] = sq; }
                else           { rnorm[row] += sp; cnorm[row] += sq; }
            }
        }
        __syncthreads();

        // ---- MFMA phase: 4 k-steps of 32 over this BK=128 slice ----
        #pragma unroll
        for (int ks = 0; ks < 4; ++ks) {
            const int kof = ks * 32 + quad * 8;
            short8 af[4], bfr[4];
            #pragma unroll
            for (int mi = 0; mi < 4; ++mi)
                af[mi] = *(const short8*)&As[(wrow + mi * 16 + l15) * LDSS + kof];
            #pragma unroll
            for (int ni = 0; ni < 4; ++ni)
                bfr[ni] = *(const short8*)&Bs[(wcol + ni * 16 + l15) * LDSS + kof];
            #pragma unroll
            for (int mi = 0; mi < 4; ++mi)
                #pragma unroll
                for (int ni = 0; ni < 4; ++ni)
                    acc[mi][ni] = __builtin_amdgcn_mfma_f32_16x16x32_bf16(
                        af[mi], bfr[ni], acc[mi][ni], 0, 0, 0);
        }
    }

    // ---- fused epilogue: d = sqrt(max(x2_i + y2_j - 2 S_ij, 0)) ----
    float lsum = 0.0f;
    #pragma unroll
    for (int mi = 0; mi < 4; ++mi) {
        #pragma unroll
        for (int i = 0; i < 4; ++i) {
            const int r = wrow + mi * 16 + quad * 4 + i;   // C/D: row=(lane>>4)*4+reg
            const float rv = rnorm[r];
            #pragma unroll
            for (int ni = 0; ni < 4; ++ni) {
                const int c = wcol + ni * 16 + l15;        // C/D: col=lane&15
                float d2 = rv + cnorm[c] - 2.0f * acc[mi][ni][i];
                float s = sqrtf(fmaxf(d2, 0.0f));
                if (symdiag && (r == c)) s = 0.0f;
                lsum += s;
            }
        }
    }
    #pragma unroll
    for (int off = 32; off; off >>= 1) lsum += __shfl_down(lsum, off);
    if (lane == 0) wpart[wv] = lsum;
    __syncthreads();
    if (tid == 0) {
        float bs = wpart[0] + wpart[1] + wpart[2] + wpart[3];
        atomicAdd(out, bs * (w * scale));
    }
}

// ---------------------------------------------------------------------------
extern "C" void kernel_launch(void* const* d_in, const int* in_sizes, int n_in,
                              void* d_out, int out_size, void* d_ws, size_t ws_size,
                              hipStream_t stream) {
    const float* X = (const float*)d_in[0];
    const float* Y = (const float*)d_in[1];
    const int total_elems = in_sizes[0];          // G*NPTS*DIM
    const int G = total_elems / (NPTS * DIM);     // 128

    float* out = (float*)d_out;
    hipMemsetAsync(out, 0, sizeof(float) * out_size, stream);

    const float scale = 1.0f / ((float)NPTS * (float)NPTS * (float)G);
    dim3 grid(10, G);
    mmd_fused<<<grid, 256, 0, stream>>>(X, Y, out, scale);
}

// Round 3
// 137.927 us; speedup vs baseline: 1.5020x; 1.5020x over previous
//
#include <hip/hip_runtime.h>
#include <stdint.h>

typedef __attribute__((ext_vector_type(8))) short short8;   // 8 bf16 (4 VGPRs) MFMA operand
typedef __attribute__((ext_vector_type(4))) float floatx4;  // MFMA accumulator

#define NPTS 256   // points per group
#define DIM  256   // feature dim
#define TILE 128   // output tile per block
#define BK   32    // K-step for DMA gemm
#define LDSS 40    // LDS row stride for fallback gemm (32 + 8 pad)

static __device__ __forceinline__ uint16_t bf16_rne(float f) {
    uint32_t u = __builtin_bit_cast(uint32_t, f);
    u += 0x7FFFu + ((u >> 16) & 1u);
    return (uint16_t)(u >> 16);
}
static __device__ __forceinline__ float bf16f(uint16_t h) {
    uint32_t u = ((uint32_t)h) << 16;
    return __builtin_bit_cast(float, u);
}
static __device__ __forceinline__ float trunc_bf16f(float f) {
    uint32_t u = __builtin_bit_cast(uint32_t, f) & 0xFFFF0000u;
    return __builtin_bit_cast(float, u);
}
static __device__ __forceinline__ uint32_t pack_trunc(float a, float b) {
    uint32_t ua = __builtin_bit_cast(uint32_t, a);
    uint32_t ub = __builtin_bit_cast(uint32_t, b);
    return (ua >> 16) | (ub & 0xFFFF0000u);
}

// async global->LDS DMA, 16 B per lane: lane i writes at lds_base + 16*i
static __device__ __forceinline__ void gl2lds16(const void* gsrc, void* ldst) {
    __builtin_amdgcn_global_load_lds(
        (const __attribute__((address_space(1))) unsigned int*)gsrc,
        (__attribute__((address_space(3))) unsigned int*)ldst,
        16, 0, 0);
}

// ---------------------------------------------------------------------------
// Kernel 1: per-point squared norms of the bf16-rounded points.
// BIG=true additionally writes bf16-converted X,Y to workspace (RNE).
// BIG=false uses truncation rounding (matches fallback gemm's inline convert).
// One wave per point; 16 points per 256-thread block. Pure streaming.
// ---------------------------------------------------------------------------
template<bool BIG>
__global__ __launch_bounds__(256)
void mmd_norms(const float* __restrict__ X, const float* __restrict__ Y,
               float* __restrict__ x2, float* __restrict__ y2,
               uint16_t* __restrict__ Xb, uint16_t* __restrict__ Yb, int npts) {
    int lane = threadIdx.x & 63;
    int wv   = threadIdx.x >> 6;
    int pblk = blockIdx.x * 16;
    #pragma unroll
    for (int r = 0; r < 4; ++r) {
        int p = pblk + wv + 4 * r;           // block never straddles X/Y (npts % 16 == 0)
        const float* src; float* dst; uint16_t* bdst; int pl;
        if (p < npts) { src = X; dst = x2; bdst = Xb; pl = p; }
        else          { src = Y; dst = y2; bdst = Yb; pl = p - npts; }
        const float4 v = *(const float4*)(src + (size_t)pl * DIM + lane * 4);
        float f0, f1, f2, f3;
        if (BIG) {
            uint16_t b0 = bf16_rne(v.x), b1 = bf16_rne(v.y),
                     b2 = bf16_rne(v.z), b3 = bf16_rne(v.w);
            f0 = bf16f(b0); f1 = bf16f(b1); f2 = bf16f(b2); f3 = bf16f(b3);
            ushort4 pk = { b0, b1, b2, b3 };
            *(ushort4*)(bdst + (size_t)pl * DIM + lane * 4) = pk;
        } else {
            f0 = trunc_bf16f(v.x); f1 = trunc_bf16f(v.y);
            f2 = trunc_bf16f(v.z); f3 = trunc_bf16f(v.w);
        }
        float ssq = f0 * f0 + f1 * f1 + f2 * f2 + f3 * f3;
        #pragma unroll
        for (int off = 32; off; off >>= 1) ssq += __shfl_down(ssq, off);
        if (lane == 0) dst[pl] = ssq;
    }
}

// ---------------------------------------------------------------------------
// Tile decode shared by both gemms. grid = (10, G):
// t 0..3 = XY (w=+1), 4..6 = XX upper (w=-0.5/-1/-0.5), 7..9 = YY upper.
// Off-diagonal symmetric tiles counted twice via weight.
// ---------------------------------------------------------------------------
static __device__ __forceinline__ void tile_decode(int t, int& ptype, int& ti, int& tj, float& w) {
    if (t < 4)      { ptype = 0; ti = t >> 1; tj = t & 1; w = 1.0f; }
    else if (t < 7) { int u = t - 4; ptype = 1; ti = (u == 2); tj = (u >= 1); w = (u == 1) ? -1.0f : -0.5f; }
    else            { int u = t - 7; ptype = 2; ti = (u == 2); tj = (u >= 1); w = (u == 1) ? -1.0f : -0.5f; }
}

// ---------------------------------------------------------------------------
// Kernel 2 (primary): 128x128x256 Gram tile from precomputed bf16, staged via
// global_load_lds width=16 (m97 structure), double-buffered BK=32, fused
// distance epilogue + block reduce + one atomicAdd.
// LDS: 2 x (8 KB A + 8 KB B) + norms ~ 34 KB -> 3-4 blocks/CU.
// ---------------------------------------------------------------------------
__global__ __launch_bounds__(256)
void mmd_gemm_dma(const uint16_t* __restrict__ Xb, const uint16_t* __restrict__ Yb,
                  const float* __restrict__ x2, const float* __restrict__ y2,
                  float* __restrict__ out, float scale) {
    const int g = blockIdx.y;
    int ptype, ti, tj; float w;
    tile_decode(blockIdx.x, ptype, ti, tj, w);

    const uint16_t *Pb, *Qb; const float *rn_g, *cn_g;
    if (ptype == 0)      { Pb = Xb; Qb = Yb; rn_g = x2; cn_g = y2; }
    else if (ptype == 1) { Pb = Xb; Qb = Xb; rn_g = x2; cn_g = x2; }
    else                 { Pb = Yb; Qb = Yb; rn_g = y2; cn_g = y2; }
    const bool symdiag = (ptype != 0) && (ti == tj);

    const size_t prow0 = (size_t)g * NPTS + (size_t)ti * TILE;
    const size_t qrow0 = (size_t)g * NPTS + (size_t)tj * TILE;

    __shared__ uint16_t As[2][TILE * BK];   // 8 KB per buffer
    __shared__ uint16_t Bs[2][TILE * BK];
    __shared__ float rnorm[TILE];
    __shared__ float cnorm[TILE];
    __shared__ float wpart[4];

    const int tid  = threadIdx.x;
    const int lane = tid & 63;
    const int wv   = tid >> 6;
    const int wrow = (wv >> 1) * 64;
    const int wcol = (wv & 1) * 64;
    const int quad = lane >> 4;
    const int l15  = lane & 15;

    // norms staged to LDS up front (barrier inside K-loop orders vs epilogue)
    if (tid < TILE) rnorm[tid] = rn_g[prow0 + tid];
    else            cnorm[tid - TILE] = cn_g[qrow0 + tid - TILE];

    // staging geometry: one DMA instruction = 16 rows x 64 B (1 KB).
    // wave wv owns rows [wv*32, wv*32+32) = 2 chunks per matrix.
    const int r0a  = wv * 32;
    const int srow = lane >> 2;              // row within chunk
    const int scol = (lane & 3) << 3;        // bf16-elem col offset (0,8,16,24)
    const uint16_t* pA = Pb + (prow0 + r0a + srow) * DIM + scol;
    const uint16_t* pB = Qb + (qrow0 + r0a + srow) * DIM + scol;

    floatx4 acc[4][4];
    #pragma unroll
    for (int i = 0; i < 4; ++i)
        #pragma unroll
        for (int j = 0; j < 4; ++j) acc[i][j] = (floatx4)0.0f;

    // prologue DMA for iter 0
    {
        gl2lds16(pA,            &As[0][(r0a     ) * BK]);
        gl2lds16(pA + 16 * DIM, &As[0][(r0a + 16) * BK]);
        gl2lds16(pB,            &Bs[0][(r0a     ) * BK]);
        gl2lds16(pB + 16 * DIM, &Bs[0][(r0a + 16) * BK]);
    }

    #pragma unroll
    for (int it = 0; it < DIM / BK; ++it) {
        const int b = it & 1;
        __syncthreads();   // drains DMA(it) (compiler vmcnt(0)); buf b^1 free for prefetch

        if (it < DIM / BK - 1) {            // prefetch iter it+1 into other buffer
            const int kk = (it + 1) * BK;
            gl2lds16(pA + kk,            &As[b ^ 1][(r0a     ) * BK]);
            gl2lds16(pA + 16 * DIM + kk, &As[b ^ 1][(r0a + 16) * BK]);
            gl2lds16(pB + kk,            &Bs[b ^ 1][(r0a     ) * BK]);
            gl2lds16(pB + 16 * DIM + kk, &Bs[b ^ 1][(r0a + 16) * BK]);
        }

        short8 af[4], bfr[4];
        #pragma unroll
        for (int mi = 0; mi < 4; ++mi)
            af[mi] = *(const short8*)&As[b][(wrow + mi * 16 + l15) * BK + quad * 8];
        #pragma unroll
        for (int ni = 0; ni < 4; ++ni)
            bfr[ni] = *(const short8*)&Bs[b][(wcol + ni * 16 + l15) * BK + quad * 8];
        #pragma unroll
        for (int mi = 0; mi < 4; ++mi)
            #pragma unroll
            for (int ni = 0; ni < 4; ++ni)
                acc[mi][ni] = __builtin_amdgcn_mfma_f32_16x16x32_bf16(
                    af[mi], bfr[ni], acc[mi][ni], 0, 0, 0);
    }

    // fused epilogue: d = sqrt(max(x2_i + y2_j - 2 S_ij, 0)), zero diag for XX/YY
    float lsum = 0.0f;
    #pragma unroll
    for (int mi = 0; mi < 4; ++mi) {
        #pragma unroll
        for (int i = 0; i < 4; ++i) {
            const int r = wrow + mi * 16 + quad * 4 + i;   // C/D: row=(lane>>4)*4+reg
            const float rv = rnorm[r];
            #pragma unroll
            for (int ni = 0; ni < 4; ++ni) {
                const int c = wcol + ni * 16 + l15;        // C/D: col=lane&15
                float d2 = rv + cnorm[c] - 2.0f * acc[mi][ni][i];
                float s = sqrtf(fmaxf(d2, 0.0f));
                if (symdiag && (r == c)) s = 0.0f;
                lsum += s;
            }
        }
    }
    #pragma unroll
    for (int off = 32; off; off >>= 1) lsum += __shfl_down(lsum, off);
    if (lane == 0) wpart[wv] = lsum;
    __syncthreads();
    if (tid == 0) {
        float bs = wpart[0] + wpart[1] + wpart[2] + wpart[3];
        atomicAdd(out, bs * (w * scale));
    }
}

// ---------------------------------------------------------------------------
// Kernel 2 (fallback, small ws): round-1 manual-staging gemm from fp32 with
// truncation convert. Only used if workspace can't hold the bf16 copies.
// ---------------------------------------------------------------------------
__global__ __launch_bounds__(256)
void mmd_gemm_fb(const float* __restrict__ X, const float* __restrict__ Y,
                 const float* __restrict__ x2, const float* __restrict__ y2,
                 float* __restrict__ out, float scale) {
    const int g = blockIdx.y;
    int ptype, ti, tj; float w;
    tile_decode(blockIdx.x, ptype, ti, tj, w);

    const float *Pf, *Qf, *rn_g, *cn_g;
    if (ptype == 0)      { Pf = X; Qf = Y; rn_g = x2; cn_g = y2; }
    else if (ptype == 1) { Pf = X; Qf = X; rn_g = x2; cn_g = x2; }
    else                 { Pf = Y; Qf = Y; rn_g = y2; cn_g = y2; }
    const bool symdiag = (ptype != 0) && (ti == tj);

    const size_t prow0 = (size_t)g * NPTS + (size_t)ti * TILE;
    const size_t qrow0 = (size_t)g * NPTS + (size_t)tj * TILE;

    __shared__ uint16_t As[TILE * LDSS];
    __shared__ uint16_t Bs[TILE * LDSS];
    __shared__ float rnorm[TILE];
    __shared__ float cnorm[TILE];
    __shared__ float wpart[4];

    const int tid  = threadIdx.x;
    const int lane = tid & 63;
    const int wv   = tid >> 6;
    const int wrow = (wv >> 1) * 64;
    const int wcol = (wv & 1) * 64;
    const int quad = lane >> 4;
    const int l15  = lane & 15;

    floatx4 acc[4][4];
    #pragma unroll
    for (int i = 0; i < 4; ++i)
        #pragma unroll
        for (int j = 0; j < 4; ++j) acc[i][j] = (floatx4)0.0f;

    for (int kk = 0; kk < DIM; kk += BK) {
        __syncthreads();
        #pragma unroll
        for (int i = 0; i < 4; ++i) {
            int f = tid + i * 256;
            int row = f >> 3, c0 = (f & 7) * 4;
            float4 v = *(const float4*)(Pf + (prow0 + row) * DIM + kk + c0);
            uint2 pk = { pack_trunc(v.x, v.y), pack_trunc(v.z, v.w) };
            *(uint2*)&As[row * LDSS + c0] = pk;
            v = *(const float4*)(Qf + (qrow0 + row) * DIM + kk + c0);
            uint2 pk2 = { pack_trunc(v.x, v.y), pack_trunc(v.z, v.w) };
            *(uint2*)&Bs[row * LDSS + c0] = pk2;
        }
        __syncthreads();

        short8 af[4], bfr[4];
        #pragma unroll
        for (int mi = 0; mi < 4; ++mi)
            af[mi] = *(const short8*)&As[(wrow + mi * 16 + l15) * LDSS + quad * 8];
        #pragma unroll
        for (int ni = 0; ni < 4; ++ni)
            bfr[ni] = *(const short8*)&Bs[(wcol + ni * 16 + l15) * LDSS + quad * 8];
        #pragma unroll
        for (int mi = 0; mi < 4; ++mi)
            #pragma unroll
            for (int ni = 0; ni < 4; ++ni)
                acc[mi][ni] = __builtin_amdgcn_mfma_f32_16x16x32_bf16(
                    af[mi], bfr[ni], acc[mi][ni], 0, 0, 0);
    }

    __syncthreads();
    if (tid < TILE) rnorm[tid] = rn_g[prow0 + tid];
    else            cnorm[tid - TILE] = cn_g[qrow0 + tid - TILE];
    __syncthreads();

    float lsum = 0.0f;
    #pragma unroll
    for (int mi = 0; mi < 4; ++mi) {
        #pragma unroll
        for (int i = 0; i < 4; ++i) {
            int r = wrow + mi * 16 + quad * 4 + i;
            float rv = rnorm[r];
            #pragma unroll
            for (int ni = 0; ni < 4; ++ni) {
                int c = wcol + ni * 16 + l15;
                float d2 = rv + cnorm[c] - 2.0f * acc[mi][ni][i];
                float s = sqrtf(fmaxf(d2, 0.0f));
                if (symdiag && (r == c)) s = 0.0f;
                lsum += s;
            }
        }
    }
    #pragma unroll
    for (int off = 32; off; off >>= 1) lsum += __shfl_down(lsum, off);
    if (lane == 0) wpart[wv] = lsum;
    __syncthreads();
    if (tid == 0) {
        float bs = wpart[0] + wpart[1] + wpart[2] + wpart[3];
        atomicAdd(out, bs * (w * scale));
    }
}

// ---------------------------------------------------------------------------
extern "C" void kernel_launch(void* const* d_in, const int* in_sizes, int n_in,
                              void* d_out, int out_size, void* d_ws, size_t ws_size,
                              hipStream_t stream) {
    const float* X = (const float*)d_in[0];
    const float* Y = (const float*)d_in[1];
    const int total_elems = in_sizes[0];          // G*NPTS*DIM
    const int npts = total_elems / DIM;           // 32768
    const int G = npts / NPTS;                    // 128

    float* x2 = (float*)d_ws;
    float* y2 = x2 + npts;
    uint16_t* Xb = (uint16_t*)(y2 + npts);
    uint16_t* Yb = Xb + (size_t)total_elems;

    const size_t need_big = (size_t)npts * 2 * sizeof(float)
                          + (size_t)total_elems * 2 * sizeof(uint16_t);
    const bool big = ws_size >= need_big;

    float* out = (float*)d_out;
    hipMemsetAsync(out, 0, sizeof(float) * out_size, stream);

    const int nblk = (2 * npts) / 16;
    if (big) mmd_norms<true ><<<nblk, 256, 0, stream>>>(X, Y, x2, y2, Xb, Yb, npts);
    else     mmd_norms<false><<<nblk, 256, 0, stream>>>(X, Y, x2, y2, Xb, Yb, npts);

    const float scale = 1.0f / ((float)NPTS * (float)NPTS * (float)G);
    dim3 grid(10, G);
    if (big) mmd_gemm_dma<<<grid, 256, 0, stream>>>(Xb, Yb, x2, y2, out, scale);
    else     mmd_gemm_fb <<<grid, 256, 0, stream>>>(X, Y, x2, y2, out, scale);
}